// Round 5
// baseline (260.898 us; speedup 1.0000x reference)
//
#include <hip/hip_runtime.h>

#define EPSF 1e-12f
#define FLTMAX 3.402823466e+38f

constexpr int B = 8, V = 6890, F = 13776, N = 4096;
constexpr int BF = B * F;
constexpr int BN = B * N;
constexpr int CHUNK = 512;
constexpr int NCHUNK = (F + CHUNK - 1) / CHUNK;   // 27
constexpr int SCAN_BLOCKS = B * NCHUNK;           // 216
constexpr int NGROUP = 128;                       // 8 b x 16 nc

// Order-preserving float <-> uint encode (total order incl. negatives).
__device__ __forceinline__ unsigned enc_f(float f) {
  unsigned b = __float_as_uint(f);
  return (b & 0x80000000u) ? ~b : (b | 0x80000000u);
}
__device__ __forceinline__ float dec_f(unsigned u) {
  return (u & 0x80000000u) ? __uint_as_float(u & 0x7FFFFFFFu) : __uint_as_float(~u);
}

__device__ __forceinline__ float block_sum_256(float v, float* s4) {
  #pragma unroll
  for (int off = 32; off > 0; off >>= 1) v += __shfl_down(v, off, 64);
  __syncthreads();
  if ((threadIdx.x & 63) == 0) s4[threadIdx.x >> 6] = v;
  __syncthreads();
  return s4[0] + s4[1] + s4[2] + s4[3];
}

__device__ __forceinline__ float face_geom(const float* __restrict__ pv,
                                           const int* __restrict__ pf,
                                           int b, int f, float4* __restrict__ nrm4,
                                           float& es) {
  if (f >= F) return 0.f;
  int i0 = pf[f * 3 + 0], i1 = pf[f * 3 + 1], i2 = pf[f * 3 + 2];
  const float* vb = pv + (size_t)b * V * 3;
  float x0 = vb[i0 * 3 + 0], y0 = vb[i0 * 3 + 1], z0 = vb[i0 * 3 + 2];
  float x1 = vb[i1 * 3 + 0], y1 = vb[i1 * 3 + 1], z1 = vb[i1 * 3 + 2];
  float x2 = vb[i2 * 3 + 0], y2 = vb[i2 * 3 + 1], z2 = vb[i2 * 3 + 2];
  float ax = x1 - x0, ay = y1 - y0, az = z1 - z0;
  float bx = x2 - x0, by = y2 - y0, bz = z2 - z0;
  float cx = ay * bz - az * by;
  float cy = az * bx - ax * bz;
  float cz = ax * by - ay * bx;
  float cn = sqrtf(cx * cx + cy * cy + cz * cz);
  float inv = 1.f / (cn + EPSF);
  nrm4[(size_t)b * F + f] = make_float4(cx * inv, cy * inv, cz * inv, 0.f);
  float ex = x0 - x1, ey = y0 - y1, ez = z0 - z1;
  es += ex * ex + ey * ey + ez * ez;
  ex = x1 - x2; ey = y1 - y2; ez = z1 - z2;
  es += ex * ex + ey * ey + ez * ez;
  es += bx * bx + by * by + bz * bz;
  return 0.5f * cn;
}

// K1: face geometry + per-chunk scan + all init (best arrays, counters, acc).
__global__ __launch_bounds__(256) void scan_faces_kernel(
    const float* __restrict__ pv, const int* __restrict__ pf,
    float* __restrict__ cdf, float* __restrict__ csum, float4* __restrict__ nrm4,
    float* __restrict__ edgep,
    unsigned long long* __restrict__ best1, unsigned* __restrict__ best2,
    float* __restrict__ acc, unsigned* __restrict__ cnt, unsigned* __restrict__ gcnt) {
  __shared__ float wsum[4];
  __shared__ float s4[4];
  int b = blockIdx.x / NCHUNK, ck = blockIdx.x % NCHUNK;
  int lane = threadIdx.x & 63, wid = threadIdx.x >> 6;

  int gid = blockIdx.x * 256 + threadIdx.x;
  if (gid < BN) { best1[gid] = ~0ull; best2[gid] = ~0u; }
  if (gid < 2) acc[gid] = 0.f;
  if (gid == 2) *cnt = 0u;
  if (gid < NGROUP) gcnt[gid] = 0u;

  int f0 = ck * CHUNK + 2 * threadIdx.x;
  float es = 0.f;
  float a0 = face_geom(pv, pf, b, f0, nrm4, es);
  float a1 = face_geom(pv, pf, b, f0 + 1, nrm4, es);
  float ts = a0 + a1;
  float x = ts;
  #pragma unroll
  for (int off = 1; off < 64; off <<= 1) {
    float y = __shfl_up(x, off, 64);
    if (lane >= off) x += y;
  }
  if (lane == 63) wsum[wid] = x;
  __syncthreads();
  float woff = 0.f;
  for (int w = 0; w < wid; ++w) woff += wsum[w];
  float excl = woff + x - ts;
  size_t g0 = (size_t)b * F + f0;
  if (f0 < F) cdf[g0] = excl + a0;
  if (f0 + 1 < F) cdf[g0 + 1] = excl + ts;
  if (threadIdx.x == 255) csum[blockIdx.x] = woff + x;   // raw chunk total

  float te = block_sum_256(es, s4);
  if (threadIdx.x == 0) edgep[blockIdx.x] = te;
}

// K2: sample 2*B*N points (on-the-fly chunk-total scan + in-chunk binary search).
__global__ __launch_bounds__(256) void sample_kernel(
    const float* __restrict__ pv, const int* __restrict__ pf,
    const float* __restrict__ cdf, const float* __restrict__ csum,
    const float4* __restrict__ nrm4,
    const float* __restrict__ rp, const float* __restrict__ rg,
    float4* __restrict__ pc4, float4* __restrict__ pn4,
    float4* __restrict__ gc4, float4* __restrict__ gn4) {
  int idx = blockIdx.x * 256 + threadIdx.x;
  if (idx >= 2 * BN) return;
  int set = (idx >= BN) ? 1 : 0;
  int i = idx - set * BN;
  int b = i / N;
  const float* r = (set ? rg : rp) + (size_t)i * 3;
  float u = r[0], r1 = r[1], r2 = r[2];

  const float* cs = csum + b * NCHUNK;
  float total = 0.f;
  #pragma unroll
  for (int k2 = 0; k2 < NCHUNK; ++k2) total += cs[k2];
  float target = u * (total + EPSF);

  int k = 0;
  float s = cs[0];
  while (s < target && k < NCHUNK - 1) { ++k; s += cs[k]; }
  float prefix = s - cs[k];
  float t2 = target - prefix;

  const float* c = cdf + (size_t)b * F + k * CHUNK;
  int base = k * CHUNK;
  int lo = 0, hi = CHUNK;
  while (lo < hi) {
    int mid = (lo + hi) >> 1;
    float v = (base + mid < F) ? c[mid] : FLTMAX;
    if (v < t2) lo = mid + 1; else hi = mid;
  }
  int f = base + lo;
  if (f > F - 1) f = F - 1;

  int i0 = pf[f * 3 + 0], i1 = pf[f * 3 + 1], i2 = pf[f * 3 + 2];
  const float* vb = pv + (size_t)b * V * 3;
  float su = sqrtf(r1);
  float w0 = 1.f - su, w1 = su * (1.f - r2), w2 = su * r2;
  float px = w0 * vb[i0 * 3 + 0] + w1 * vb[i1 * 3 + 0] + w2 * vb[i2 * 3 + 0];
  float py = w0 * vb[i0 * 3 + 1] + w1 * vb[i1 * 3 + 1] + w2 * vb[i2 * 3 + 1];
  float pz = w0 * vb[i0 * 3 + 2] + w1 * vb[i1 * 3 + 2] + w2 * vb[i2 * 3 + 2];
  float4* pts = (set ? gc4 : pc4);
  float4* pns = (set ? gn4 : pn4);
  pts[i] = make_float4(px, py, pz, px * px + py * py + pz * pz);
  pns[i] = nrm4[(size_t)b * F + f];
}

// K3: balanced chamfer + ticketed finalize. Grid 2048 = b(8) x nc(16) x mc(16).
// Each block: its dist1 rows AND dist2 rows vs one 256-point m-chunk, interleaved.
// Last block of each (b,nc) group finalizes those 256 rows; last group writes out.
__global__ __launch_bounds__(256, 8) void chamfer_kernel(
    const float4* __restrict__ pc4, const float4* __restrict__ gc4,
    const float4* __restrict__ pn4, const float4* __restrict__ gn4,
    const float* __restrict__ edgep,
    unsigned long long* __restrict__ best1, unsigned* __restrict__ best2,
    float* __restrict__ acc, unsigned* __restrict__ cnt, unsigned* __restrict__ gcnt,
    float* __restrict__ out) {
  __shared__ float s4[4];
  __shared__ unsigned tk;
  const int tid = threadIdx.x;
  const int b = blockIdx.x >> 8;
  const int nc = (blockIdx.x >> 4) & 15, mc = blockIdx.x & 15;
  const int n = nc * 256 + tid;
  const int mbase = mc * 256;
  const size_t row = (size_t)b * N + n;

  const float4 pa = pc4[row];                 // dist1 row point
  const float4 pb = gc4[row];                 // dist2 row point
  const float4* __restrict__ sa = gc4 + (size_t)b * N + mbase;   // dist1 m-stream
  const float4* __restrict__ sb = pc4 + (size_t)b * N + mbase;   // dist2 m-stream
  const float qax = -2.f * pa.x, qay = -2.f * pa.y, qaz = -2.f * pa.z;
  const float qbx = -2.f * pb.x, qby = -2.f * pb.y, qbz = -2.f * pb.z;
  const float ppa = pa.w, ppb = pb.w;

  float ad0 = FLTMAX, ad1 = FLTMAX;           // dist1 chains (argmin kept)
  int ai0 = 0, ai1 = 0;
  float bd0 = FLTMAX, bd1 = FLTMAX;           // dist2 chains (min only)
  #pragma unroll 2
  for (int j = 0; j < 256; j += 2) {
    float4 ta0 = sa[j], ta1 = sa[j + 1];
    float4 tb0 = sb[j], tb1 = sb[j + 1];
    float da0 = fmaf(qax, ta0.x, fmaf(qay, ta0.y, fmaf(qaz, ta0.z, ppa + ta0.w)));
    float da1 = fmaf(qax, ta1.x, fmaf(qay, ta1.y, fmaf(qaz, ta1.z, ppa + ta1.w)));
    float db0 = fmaf(qbx, tb0.x, fmaf(qby, tb0.y, fmaf(qbz, tb0.z, ppb + tb0.w)));
    float db1 = fmaf(qbx, tb1.x, fmaf(qby, tb1.y, fmaf(qbz, tb1.z, ppb + tb1.w)));
    if (da0 < ad0) { ad0 = da0; ai0 = mbase + j; }
    if (da1 < ad1) { ad1 = da1; ai1 = mbase + j + 1; }
    bd0 = fminf(bd0, db0);
    bd1 = fminf(bd1, db1);
  }
  // exact first-occurrence merge of the two dist1 chains
  if (ad1 < ad0 || (ad1 == ad0 && ai1 < ai0)) { ad0 = ad1; ai0 = ai1; }
  unsigned long long key = ((unsigned long long)enc_f(ad0) << 32) | (unsigned)ai0;
  atomicMin(&best1[row], key);
  atomicMin(&best2[row], enc_f(fminf(bd0, bd1)));

  // ---- group ticket: last of the 16 mc-blocks finalizes rows of (b,nc) ----
  __threadfence();
  if (tid == 0) tk = atomicAdd(&gcnt[(b << 4) + nc], 1u);
  __syncthreads();
  if (tk == 15) {
    __threadfence();
    unsigned long long k1 = __hip_atomic_load(&best1[row], __ATOMIC_RELAXED,
                                              __HIP_MEMORY_SCOPE_AGENT);
    unsigned k2 = __hip_atomic_load(&best2[row], __ATOMIC_RELAXED,
                                    __HIP_MEMORY_SCOPE_AGENT);
    float d1 = dec_f((unsigned)(k1 >> 32));
    int m = (int)(unsigned)(k1 & 0xFFFFFFFFull);
    float d2 = dec_f(k2);
    float4 a = pn4[row];
    float4 g = gn4[((size_t)b << 12) + m];
    float nl = 1.f - fabsf(a.x * g.x + a.y * g.y + a.z * g.z);
    float sd = block_sum_256(d1 + d2, s4);
    float sn = block_sum_256(nl, s4);
    if (tid == 0) {
      atomicAdd(&acc[0], sd);
      atomicAdd(&acc[1], sn);
      __threadfence();
      tk = atomicAdd(cnt, 1u);
    }
    __syncthreads();
    if (tk == NGROUP - 1) {                  // last finalize group -> fold + out
      float e = (tid < SCAN_BLOCKS) ? edgep[tid] : 0.f;
      float te = block_sum_256(e, s4);
      if (tid == 0) {
        float chamf = atomicAdd(&acc[0], 0.f);
        float nsum  = atomicAdd(&acc[1], 0.f);
        float inv_bn = 1.f / (float)BN;
        out[0] = chamf * inv_bn + 0.1f * (nsum * inv_bn) + 0.5f * (te / (3.f * (float)BF));
      }
    }
  }
}

extern "C" void kernel_launch(void* const* d_in, const int* in_sizes, int n_in,
                              void* d_out, int out_size, void* d_ws, size_t ws_size,
                              hipStream_t stream) {
  const float* pv = (const float*)d_in[0];   // predicted_vertices [B,V,3]
  const int*   pf = (const int*)d_in[1];     // predicted_faces [F,3]
  // d_in[2]/d_in[3] (gt mesh) are unused by the reference.
  const float* rp = (const float*)d_in[4];   // rand_pred [B,N,3]
  const float* rg = (const float*)d_in[5];   // rand_gt   [B,N,3]
  float* out = (float*)d_out;

  unsigned long long* best1 = (unsigned long long*)d_ws;   // BN u64
  unsigned* best2 = (unsigned*)(best1 + BN);               // BN u32
  float4* pc4  = (float4*)(best2 + BN);                    // BN
  float4* pn4  = pc4 + BN;                                 // BN
  float4* gc4  = pn4 + BN;                                 // BN
  float4* gn4  = gc4 + BN;                                 // BN
  float4* nrm4 = gn4 + BN;                                 // BF
  float* cdf   = (float*)(nrm4 + BF);                      // BF
  float* csum  = cdf + BF;                                 // 216
  float* edgep = csum + SCAN_BLOCKS;                       // 216
  float* acc   = edgep + SCAN_BLOCKS;                      // 2
  unsigned* cnt  = (unsigned*)(acc + 2);                   // 1
  unsigned* gcnt = cnt + 1;                                // 128

  scan_faces_kernel<<<SCAN_BLOCKS, 256, 0, stream>>>(pv, pf, cdf, csum, nrm4, edgep,
                                                     best1, best2, acc, cnt, gcnt);
  sample_kernel<<<(2 * BN) / 256, 256, 0, stream>>>(pv, pf, cdf, csum, nrm4,
                                                    rp, rg, pc4, pn4, gc4, gn4);
  chamfer_kernel<<<2048, 256, 0, stream>>>(pc4, gc4, pn4, gn4, edgep,
                                           best1, best2, acc, cnt, gcnt, out);
}

// Round 7
// 149.728 us; speedup vs baseline: 1.7425x; 1.7425x over previous
//
#include <hip/hip_runtime.h>

#define EPSF 1e-12f
#define FLTMAX 3.402823466e+38f

constexpr int B = 8, V = 6890, F = 13776, N = 4096;
constexpr int BF = B * F;
constexpr int BN = B * N;
constexpr int CHUNK = 512;
constexpr int NCHUNK = (F + CHUNK - 1) / CHUNK;   // 27
constexpr int SCAN_BLOCKS = B * NCHUNK;           // 216
constexpr int NGROUP = 128;                       // 8 b x 16 nc
constexpr int MCHUNKS = 8;                        // m-chunks per group

// Order-preserving float <-> uint encode (total order incl. negatives).
__device__ __forceinline__ unsigned enc_f(float f) {
  unsigned b = __float_as_uint(f);
  return (b & 0x80000000u) ? ~b : (b | 0x80000000u);
}
__device__ __forceinline__ float dec_f(unsigned u) {
  return (u & 0x80000000u) ? __uint_as_float(u & 0x7FFFFFFFu) : __uint_as_float(~u);
}

__device__ __forceinline__ float block_sum_256(float v, float* s4) {
  #pragma unroll
  for (int off = 32; off > 0; off >>= 1) v += __shfl_down(v, off, 64);
  __syncthreads();
  if ((threadIdx.x & 63) == 0) s4[threadIdx.x >> 6] = v;
  __syncthreads();
  return s4[0] + s4[1] + s4[2] + s4[3];
}

__device__ __forceinline__ float face_geom(const float* __restrict__ pv,
                                           const int* __restrict__ pf,
                                           int b, int f, float4* __restrict__ nrm4,
                                           float& es) {
  if (f >= F) return 0.f;
  int i0 = pf[f * 3 + 0], i1 = pf[f * 3 + 1], i2 = pf[f * 3 + 2];
  const float* vb = pv + (size_t)b * V * 3;
  float x0 = vb[i0 * 3 + 0], y0 = vb[i0 * 3 + 1], z0 = vb[i0 * 3 + 2];
  float x1 = vb[i1 * 3 + 0], y1 = vb[i1 * 3 + 1], z1 = vb[i1 * 3 + 2];
  float x2 = vb[i2 * 3 + 0], y2 = vb[i2 * 3 + 1], z2 = vb[i2 * 3 + 2];
  float ax = x1 - x0, ay = y1 - y0, az = z1 - z0;
  float bx = x2 - x0, by = y2 - y0, bz = z2 - z0;
  float cx = ay * bz - az * by;
  float cy = az * bx - ax * bz;
  float cz = ax * by - ay * bx;
  float cn = sqrtf(cx * cx + cy * cy + cz * cz);
  float inv = 1.f / (cn + EPSF);
  nrm4[(size_t)b * F + f] = make_float4(cx * inv, cy * inv, cz * inv, 0.f);
  float ex = x0 - x1, ey = y0 - y1, ez = z0 - z1;
  es += ex * ex + ey * ey + ez * ez;
  ex = x1 - x2; ey = y1 - y2; ez = z1 - z2;
  es += ex * ex + ey * ey + ez * ez;
  es += bx * bx + by * by + bz * bz;
  return 0.5f * cn;
}

// K1: face geometry + per-chunk scan + all init (best arrays, counters, acc).
__global__ __launch_bounds__(256) void scan_faces_kernel(
    const float* __restrict__ pv, const int* __restrict__ pf,
    float* __restrict__ cdf, float* __restrict__ csum, float4* __restrict__ nrm4,
    float* __restrict__ edgep,
    unsigned long long* __restrict__ best1, unsigned* __restrict__ best2,
    float* __restrict__ acc, unsigned* __restrict__ cnt, unsigned* __restrict__ gcnt) {
  __shared__ float wsum[4];
  __shared__ float s4[4];
  int b = blockIdx.x / NCHUNK, ck = blockIdx.x % NCHUNK;
  int lane = threadIdx.x & 63, wid = threadIdx.x >> 6;

  int gid = blockIdx.x * 256 + threadIdx.x;
  if (gid < BN) { best1[gid] = ~0ull; best2[gid] = ~0u; }
  if (gid < 2) acc[gid] = 0.f;
  if (gid == 2) *cnt = 0u;
  if (gid < NGROUP) gcnt[gid] = 0u;

  int f0 = ck * CHUNK + 2 * threadIdx.x;
  float es = 0.f;
  float a0 = face_geom(pv, pf, b, f0, nrm4, es);
  float a1 = face_geom(pv, pf, b, f0 + 1, nrm4, es);
  float ts = a0 + a1;
  float x = ts;
  #pragma unroll
  for (int off = 1; off < 64; off <<= 1) {
    float y = __shfl_up(x, off, 64);
    if (lane >= off) x += y;
  }
  if (lane == 63) wsum[wid] = x;
  __syncthreads();
  float woff = 0.f;
  for (int w = 0; w < wid; ++w) woff += wsum[w];
  float excl = woff + x - ts;
  size_t g0 = (size_t)b * F + f0;
  if (f0 < F) cdf[g0] = excl + a0;
  if (f0 + 1 < F) cdf[g0 + 1] = excl + ts;
  if (threadIdx.x == 255) csum[blockIdx.x] = woff + x;   // raw chunk total

  float te = block_sum_256(es, s4);
  if (threadIdx.x == 0) edgep[blockIdx.x] = te;
}

// K2: sample 2*B*N points (on-the-fly chunk-total scan + in-chunk binary search).
__global__ __launch_bounds__(256) void sample_kernel(
    const float* __restrict__ pv, const int* __restrict__ pf,
    const float* __restrict__ cdf, const float* __restrict__ csum,
    const float4* __restrict__ nrm4,
    const float* __restrict__ rp, const float* __restrict__ rg,
    float4* __restrict__ pc4, float4* __restrict__ pn4,
    float4* __restrict__ gc4, float4* __restrict__ gn4) {
  int idx = blockIdx.x * 256 + threadIdx.x;
  if (idx >= 2 * BN) return;
  int set = (idx >= BN) ? 1 : 0;
  int i = idx - set * BN;
  int b = i / N;
  const float* r = (set ? rg : rp) + (size_t)i * 3;
  float u = r[0], r1 = r[1], r2 = r[2];

  const float* cs = csum + b * NCHUNK;
  float total = 0.f;
  #pragma unroll
  for (int k2 = 0; k2 < NCHUNK; ++k2) total += cs[k2];
  float target = u * (total + EPSF);

  int k = 0;
  float s = cs[0];
  while (s < target && k < NCHUNK - 1) { ++k; s += cs[k]; }
  float prefix = s - cs[k];
  float t2 = target - prefix;

  const float* c = cdf + (size_t)b * F + k * CHUNK;
  int base = k * CHUNK;
  int lo = 0, hi = CHUNK;
  while (lo < hi) {
    int mid = (lo + hi) >> 1;
    float v = (base + mid < F) ? c[mid] : FLTMAX;
    if (v < t2) lo = mid + 1; else hi = mid;
  }
  int f = base + lo;
  if (f > F - 1) f = F - 1;

  int i0 = pf[f * 3 + 0], i1 = pf[f * 3 + 1], i2 = pf[f * 3 + 2];
  const float* vb = pv + (size_t)b * V * 3;
  float su = sqrtf(r1);
  float w0 = 1.f - su, w1 = su * (1.f - r2), w2 = su * r2;
  float px = w0 * vb[i0 * 3 + 0] + w1 * vb[i1 * 3 + 0] + w2 * vb[i2 * 3 + 0];
  float py = w0 * vb[i0 * 3 + 1] + w1 * vb[i1 * 3 + 1] + w2 * vb[i2 * 3 + 1];
  float pz = w0 * vb[i0 * 3 + 2] + w1 * vb[i1 * 3 + 2] + w2 * vb[i2 * 3 + 2];
  float4* pts = (set ? gc4 : pc4);
  float4* pns = (set ? gn4 : pn4);
  pts[i] = make_float4(px, py, pz, px * px + py * py + pz * pz);
  pns[i] = nrm4[(size_t)b * F + f];
}

// K3: balanced chamfer + ticketed finalize (NO device fences — bare vmcnt waits).
// Grid 1024 = b(8) x nc(16) x mc(8). Each block runs the R3-proven dist1 loop
// (4 chains, argmin) AND dist2 loop over one 512-point m-chunk -> uniform work.
// Last block of each (b,nc) group finalizes its 256 rows; last group writes out.
__global__ __launch_bounds__(256, 8) void chamfer_kernel(
    const float4* __restrict__ pc4, const float4* __restrict__ gc4,
    const float4* __restrict__ pn4, const float4* __restrict__ gn4,
    const float* __restrict__ edgep,
    unsigned long long* __restrict__ best1, unsigned* __restrict__ best2,
    float* __restrict__ acc, unsigned* __restrict__ cnt, unsigned* __restrict__ gcnt,
    float* __restrict__ out) {
  __shared__ float s4[4];
  __shared__ unsigned tk;
  const int tid = threadIdx.x;
  const int b = blockIdx.x >> 7;
  const int nc = (blockIdx.x >> 3) & 15, mc = blockIdx.x & 7;
  const int n = nc * 256 + tid;
  const int mbase = mc * 512;
  const size_t row = (size_t)b * N + n;

  // ---- dist1 (argmin kept): pc4 rows vs gc4 m-chunk ----
  {
    const float4 p = pc4[row];
    const float4* __restrict__ other = gc4 + (size_t)b * N + mbase;
    const float qx = -2.f * p.x, qy = -2.f * p.y, qz = -2.f * p.z;
    const float pp = p.w;
    float bd0 = FLTMAX, bd1 = FLTMAX, bd2 = FLTMAX, bd3 = FLTMAX;
    int bi0 = 0, bi1 = 0, bi2 = 0, bi3 = 0;
    #pragma unroll 2
    for (int j = 0; j < 512; j += 4) {
      float4 t0 = other[j], t1 = other[j + 1], t2 = other[j + 2], t3 = other[j + 3];
      float d0 = fmaf(qx, t0.x, fmaf(qy, t0.y, fmaf(qz, t0.z, pp + t0.w)));
      float d1 = fmaf(qx, t1.x, fmaf(qy, t1.y, fmaf(qz, t1.z, pp + t1.w)));
      float d2 = fmaf(qx, t2.x, fmaf(qy, t2.y, fmaf(qz, t2.z, pp + t2.w)));
      float d3 = fmaf(qx, t3.x, fmaf(qy, t3.y, fmaf(qz, t3.z, pp + t3.w)));
      if (d0 < bd0) { bd0 = d0; bi0 = mbase + j; }
      if (d1 < bd1) { bd1 = d1; bi1 = mbase + j + 1; }
      if (d2 < bd2) { bd2 = d2; bi2 = mbase + j + 2; }
      if (d3 < bd3) { bd3 = d3; bi3 = mbase + j + 3; }
    }
    if (bd1 < bd0 || (bd1 == bd0 && bi1 < bi0)) { bd0 = bd1; bi0 = bi1; }
    if (bd3 < bd2 || (bd3 == bd2 && bi3 < bi2)) { bd2 = bd3; bi2 = bi3; }
    if (bd2 < bd0 || (bd2 == bd0 && bi2 < bi0)) { bd0 = bd2; bi0 = bi2; }
    unsigned long long key = ((unsigned long long)enc_f(bd0) << 32) | (unsigned)bi0;
    atomicMin(&best1[row], key);
  }
  // ---- dist2 (min only): gc4 rows vs pc4 m-chunk ----
  {
    const float4 p = gc4[row];
    const float4* __restrict__ other = pc4 + (size_t)b * N + mbase;
    const float qx = -2.f * p.x, qy = -2.f * p.y, qz = -2.f * p.z;
    const float pp = p.w;
    float bda = FLTMAX, bdb = FLTMAX;
    #pragma unroll 2
    for (int j = 0; j < 512; j += 4) {
      float4 t0 = other[j], t1 = other[j + 1], t2 = other[j + 2], t3 = other[j + 3];
      float d0 = fmaf(qx, t0.x, fmaf(qy, t0.y, fmaf(qz, t0.z, pp + t0.w)));
      float d1 = fmaf(qx, t1.x, fmaf(qy, t1.y, fmaf(qz, t1.z, pp + t1.w)));
      float d2 = fmaf(qx, t2.x, fmaf(qy, t2.y, fmaf(qz, t2.z, pp + t2.w)));
      float d3 = fmaf(qx, t3.x, fmaf(qy, t3.y, fmaf(qz, t3.z, pp + t3.w)));
      bda = fminf(fminf(d0, d1), bda);   // -> v_min3
      bdb = fminf(fminf(d2, d3), bdb);
    }
    atomicMin(&best2[row], enc_f(fminf(bda, bdb)));
  }

  // Wait for THIS wave's atomics to reach the device coherence point.
  // (bare vmcnt wait — crucially NOT __threadfence(): no buffer_wbl2 L2 flush)
  __asm__ __volatile__("s_waitcnt vmcnt(0)" ::: "memory");
  if (tid == 0) tk = atomicAdd(&gcnt[(b << 4) + nc], 1u);
  __syncthreads();
  if (tk == MCHUNKS - 1) {       // last of the 8 mc-blocks: finalize (b,nc) rows
    unsigned long long k1 = __hip_atomic_load(&best1[row], __ATOMIC_RELAXED,
                                              __HIP_MEMORY_SCOPE_AGENT);
    unsigned k2 = __hip_atomic_load(&best2[row], __ATOMIC_RELAXED,
                                    __HIP_MEMORY_SCOPE_AGENT);
    float d1 = dec_f((unsigned)(k1 >> 32));
    int m = (int)(unsigned)(k1 & 0xFFFFFFFFull) & (N - 1);   // mask: free OOB insurance
    float d2 = dec_f(k2);
    float4 a = pn4[row];
    float4 g = gn4[((size_t)b << 12) + m];
    float nl = 1.f - fabsf(a.x * g.x + a.y * g.y + a.z * g.z);
    float sd = block_sum_256(d1 + d2, s4);
    float sn = block_sum_256(nl, s4);
    if (tid == 0) {
      atomicAdd(&acc[0], sd);
      atomicAdd(&acc[1], sn);
      __asm__ __volatile__("s_waitcnt vmcnt(0)" ::: "memory");
      tk = atomicAdd(cnt, 1u);
    }
    __syncthreads();
    if (tk == NGROUP - 1) {      // last finalize group -> edge fold + out
      float e = (tid < SCAN_BLOCKS) ? edgep[tid] : 0.f;
      float te = block_sum_256(e, s4);
      if (tid == 0) {
        float chamf = atomicAdd(&acc[0], 0.f);
        float nsum  = atomicAdd(&acc[1], 0.f);
        float inv_bn = 1.f / (float)BN;
        out[0] = chamf * inv_bn + 0.1f * (nsum * inv_bn) + 0.5f * (te / (3.f * (float)BF));
      }
    }
  }
}

extern "C" void kernel_launch(void* const* d_in, const int* in_sizes, int n_in,
                              void* d_out, int out_size, void* d_ws, size_t ws_size,
                              hipStream_t stream) {
  const float* pv = (const float*)d_in[0];   // predicted_vertices [B,V,3]
  const int*   pf = (const int*)d_in[1];     // predicted_faces [F,3]
  // d_in[2]/d_in[3] (gt mesh) are unused by the reference.
  const float* rp = (const float*)d_in[4];   // rand_pred [B,N,3]
  const float* rg = (const float*)d_in[5];   // rand_gt   [B,N,3]
  float* out = (float*)d_out;

  unsigned long long* best1 = (unsigned long long*)d_ws;   // BN u64
  unsigned* best2 = (unsigned*)(best1 + BN);               // BN u32
  float4* pc4  = (float4*)(best2 + BN);                    // BN
  float4* pn4  = pc4 + BN;                                 // BN
  float4* gc4  = pn4 + BN;                                 // BN
  float4* gn4  = gc4 + BN;                                 // BN
  float4* nrm4 = gn4 + BN;                                 // BF
  float* cdf   = (float*)(nrm4 + BF);                      // BF
  float* csum  = cdf + BF;                                 // 216
  float* edgep = csum + SCAN_BLOCKS;                       // 216
  float* acc   = edgep + SCAN_BLOCKS;                      // 2
  unsigned* cnt  = (unsigned*)(acc + 2);                   // 1
  unsigned* gcnt = cnt + 1;                                // 128

  scan_faces_kernel<<<SCAN_BLOCKS, 256, 0, stream>>>(pv, pf, cdf, csum, nrm4, edgep,
                                                     best1, best2, acc, cnt, gcnt);
  sample_kernel<<<(2 * BN) / 256, 256, 0, stream>>>(pv, pf, cdf, csum, nrm4,
                                                    rp, rg, pc4, pn4, gc4, gn4);
  chamfer_kernel<<<1024, 256, 0, stream>>>(pc4, gc4, pn4, gn4, edgep,
                                           best1, best2, acc, cnt, gcnt, out);
}

// Round 8
// 127.165 us; speedup vs baseline: 2.0516x; 1.1774x over previous
//
#include <hip/hip_runtime.h>

#define EPSF 1e-12f
#define FLTMAX 3.402823466e+38f

constexpr int B = 8, V = 6890, F = 13776, N = 4096;
constexpr int BF = B * F;
constexpr int BN = B * N;
constexpr int CHUNK = 512;
constexpr int NCHUNK = (F + CHUNK - 1) / CHUNK;   // 27
constexpr int SCAN_BLOCKS = B * NCHUNK;           // 216
constexpr int NGROUP = 128;                       // 8 b x 16 nc
constexpr int MCHUNKS = 16;                       // m-chunks per group (256 pts each)

// Order-preserving float <-> uint encode (total order incl. negatives).
__device__ __forceinline__ unsigned enc_f(float f) {
  unsigned b = __float_as_uint(f);
  return (b & 0x80000000u) ? ~b : (b | 0x80000000u);
}
__device__ __forceinline__ float dec_f(unsigned u) {
  return (u & 0x80000000u) ? __uint_as_float(u & 0x7FFFFFFFu) : __uint_as_float(~u);
}

__device__ __forceinline__ float block_sum_256(float v, float* s4) {
  #pragma unroll
  for (int off = 32; off > 0; off >>= 1) v += __shfl_down(v, off, 64);
  __syncthreads();
  if ((threadIdx.x & 63) == 0) s4[threadIdx.x >> 6] = v;
  __syncthreads();
  return s4[0] + s4[1] + s4[2] + s4[3];
}

__device__ __forceinline__ float face_geom(const float* __restrict__ pv,
                                           const int* __restrict__ pf,
                                           int b, int f, float4* __restrict__ nrm4,
                                           float& es) {
  if (f >= F) return 0.f;
  int i0 = pf[f * 3 + 0], i1 = pf[f * 3 + 1], i2 = pf[f * 3 + 2];
  const float* vb = pv + (size_t)b * V * 3;
  float x0 = vb[i0 * 3 + 0], y0 = vb[i0 * 3 + 1], z0 = vb[i0 * 3 + 2];
  float x1 = vb[i1 * 3 + 0], y1 = vb[i1 * 3 + 1], z1 = vb[i1 * 3 + 2];
  float x2 = vb[i2 * 3 + 0], y2 = vb[i2 * 3 + 1], z2 = vb[i2 * 3 + 2];
  float ax = x1 - x0, ay = y1 - y0, az = z1 - z0;
  float bx = x2 - x0, by = y2 - y0, bz = z2 - z0;
  float cx = ay * bz - az * by;
  float cy = az * bx - ax * bz;
  float cz = ax * by - ay * bx;
  float cn = sqrtf(cx * cx + cy * cy + cz * cz);
  float inv = 1.f / (cn + EPSF);
  nrm4[(size_t)b * F + f] = make_float4(cx * inv, cy * inv, cz * inv, 0.f);
  float ex = x0 - x1, ey = y0 - y1, ez = z0 - z1;
  es += ex * ex + ey * ey + ez * ez;
  ex = x1 - x2; ey = y1 - y2; ez = z1 - z2;
  es += ex * ex + ey * ey + ez * ez;
  es += bx * bx + by * by + bz * bz;
  return 0.5f * cn;
}

// K1: face geometry + per-chunk scan + all init (best arrays, counters, acc).
__global__ __launch_bounds__(256) void scan_faces_kernel(
    const float* __restrict__ pv, const int* __restrict__ pf,
    float* __restrict__ cdf, float* __restrict__ csum, float4* __restrict__ nrm4,
    float* __restrict__ edgep,
    unsigned long long* __restrict__ best1, unsigned* __restrict__ best2,
    float* __restrict__ acc, unsigned* __restrict__ cnt, unsigned* __restrict__ gcnt) {
  __shared__ float wsum[4];
  __shared__ float s4[4];
  int b = blockIdx.x / NCHUNK, ck = blockIdx.x % NCHUNK;
  int lane = threadIdx.x & 63, wid = threadIdx.x >> 6;

  int gid = blockIdx.x * 256 + threadIdx.x;
  if (gid < BN) { best1[gid] = ~0ull; best2[gid] = ~0u; }
  if (gid < 2) acc[gid] = 0.f;
  if (gid == 2) *cnt = 0u;
  if (gid < NGROUP) gcnt[gid] = 0u;

  int f0 = ck * CHUNK + 2 * threadIdx.x;
  float es = 0.f;
  float a0 = face_geom(pv, pf, b, f0, nrm4, es);
  float a1 = face_geom(pv, pf, b, f0 + 1, nrm4, es);
  float ts = a0 + a1;
  float x = ts;
  #pragma unroll
  for (int off = 1; off < 64; off <<= 1) {
    float y = __shfl_up(x, off, 64);
    if (lane >= off) x += y;
  }
  if (lane == 63) wsum[wid] = x;
  __syncthreads();
  float woff = 0.f;
  for (int w = 0; w < wid; ++w) woff += wsum[w];
  float excl = woff + x - ts;
  size_t g0 = (size_t)b * F + f0;
  if (f0 < F) cdf[g0] = excl + a0;
  if (f0 + 1 < F) cdf[g0 + 1] = excl + ts;
  if (threadIdx.x == 255) csum[blockIdx.x] = woff + x;   // raw chunk total

  float te = block_sum_256(es, s4);
  if (threadIdx.x == 0) edgep[blockIdx.x] = te;
}

// K2: sample 2*B*N points (on-the-fly chunk-total scan + in-chunk binary search).
__global__ __launch_bounds__(256) void sample_kernel(
    const float* __restrict__ pv, const int* __restrict__ pf,
    const float* __restrict__ cdf, const float* __restrict__ csum,
    const float4* __restrict__ nrm4,
    const float* __restrict__ rp, const float* __restrict__ rg,
    float4* __restrict__ pc4, float4* __restrict__ pn4,
    float4* __restrict__ gc4, float4* __restrict__ gn4) {
  int idx = blockIdx.x * 256 + threadIdx.x;
  if (idx >= 2 * BN) return;
  int set = (idx >= BN) ? 1 : 0;
  int i = idx - set * BN;
  int b = i / N;
  const float* r = (set ? rg : rp) + (size_t)i * 3;
  float u = r[0], r1 = r[1], r2 = r[2];

  const float* cs = csum + b * NCHUNK;
  float total = 0.f;
  #pragma unroll
  for (int k2 = 0; k2 < NCHUNK; ++k2) total += cs[k2];
  float target = u * (total + EPSF);

  int k = 0;
  float s = cs[0];
  while (s < target && k < NCHUNK - 1) { ++k; s += cs[k]; }
  float prefix = s - cs[k];
  float t2 = target - prefix;

  const float* c = cdf + (size_t)b * F + k * CHUNK;
  int base = k * CHUNK;
  int lo = 0, hi = CHUNK;
  while (lo < hi) {
    int mid = (lo + hi) >> 1;
    float v = (base + mid < F) ? c[mid] : FLTMAX;
    if (v < t2) lo = mid + 1; else hi = mid;
  }
  int f = base + lo;
  if (f > F - 1) f = F - 1;

  int i0 = pf[f * 3 + 0], i1 = pf[f * 3 + 1], i2 = pf[f * 3 + 2];
  const float* vb = pv + (size_t)b * V * 3;
  float su = sqrtf(r1);
  float w0 = 1.f - su, w1 = su * (1.f - r2), w2 = su * r2;
  float px = w0 * vb[i0 * 3 + 0] + w1 * vb[i1 * 3 + 0] + w2 * vb[i2 * 3 + 0];
  float py = w0 * vb[i0 * 3 + 1] + w1 * vb[i1 * 3 + 1] + w2 * vb[i2 * 3 + 1];
  float pz = w0 * vb[i0 * 3 + 2] + w1 * vb[i1 * 3 + 2] + w2 * vb[i2 * 3 + 2];
  float4* pts = (set ? gc4 : pc4);
  float4* pns = (set ? gn4 : pn4);
  pts[i] = make_float4(px, py, pz, px * px + py * py + pz * pz);
  pns[i] = nrm4[(size_t)b * F + f];
}

// K3: balanced chamfer + ticketed finalize. Grid 2048 = b(8) x nc(16) x mc(16).
// Each block: dist1 rows AND dist2 rows vs one 256-point m-chunk (sequential
// loops). pp (row-constant) is dropped from the fma chain and re-added after
// the min — argmin unaffected, 3 FMA/eval instead of add+3 FMA.
__global__ __launch_bounds__(256, 8) void chamfer_kernel(
    const float4* __restrict__ pc4, const float4* __restrict__ gc4,
    const float4* __restrict__ pn4, const float4* __restrict__ gn4,
    const float* __restrict__ edgep,
    unsigned long long* __restrict__ best1, unsigned* __restrict__ best2,
    float* __restrict__ acc, unsigned* __restrict__ cnt, unsigned* __restrict__ gcnt,
    float* __restrict__ out) {
  __shared__ float s4[4];
  __shared__ unsigned tk;
  const int tid = threadIdx.x;
  const int b = blockIdx.x >> 8;
  const int nc = (blockIdx.x >> 4) & 15, mc = blockIdx.x & 15;
  const int n = nc * 256 + tid;
  const int mbase = mc * 256;
  const size_t row = (size_t)b * N + n;

  // ---- dist1 (argmin kept): pc4 rows vs gc4 m-chunk ----
  {
    const float4 p = pc4[row];
    const float4* __restrict__ other = gc4 + (size_t)b * N + mbase;
    const float qx = -2.f * p.x, qy = -2.f * p.y, qz = -2.f * p.z;
    float bd0 = FLTMAX, bd1 = FLTMAX, bd2 = FLTMAX, bd3 = FLTMAX;
    int bi0 = 0, bi1 = 0, bi2 = 0, bi3 = 0;
    #pragma unroll 2
    for (int j = 0; j < 256; j += 4) {
      float4 t0 = other[j], t1 = other[j + 1], t2 = other[j + 2], t3 = other[j + 3];
      float d0 = fmaf(qx, t0.x, fmaf(qy, t0.y, fmaf(qz, t0.z, t0.w)));
      float d1 = fmaf(qx, t1.x, fmaf(qy, t1.y, fmaf(qz, t1.z, t1.w)));
      float d2 = fmaf(qx, t2.x, fmaf(qy, t2.y, fmaf(qz, t2.z, t2.w)));
      float d3 = fmaf(qx, t3.x, fmaf(qy, t3.y, fmaf(qz, t3.z, t3.w)));
      if (d0 < bd0) { bd0 = d0; bi0 = mbase + j; }
      if (d1 < bd1) { bd1 = d1; bi1 = mbase + j + 1; }
      if (d2 < bd2) { bd2 = d2; bi2 = mbase + j + 2; }
      if (d3 < bd3) { bd3 = d3; bi3 = mbase + j + 3; }
    }
    if (bd1 < bd0 || (bd1 == bd0 && bi1 < bi0)) { bd0 = bd1; bi0 = bi1; }
    if (bd3 < bd2 || (bd3 == bd2 && bi3 < bi2)) { bd2 = bd3; bi2 = bi3; }
    if (bd2 < bd0 || (bd2 == bd0 && bi2 < bi0)) { bd0 = bd2; bi0 = bi2; }
    unsigned long long key =
        ((unsigned long long)enc_f(bd0 + p.w) << 32) | (unsigned)bi0;
    atomicMin(&best1[row], key);
  }
  // ---- dist2 (min only): gc4 rows vs pc4 m-chunk ----
  {
    const float4 p = gc4[row];
    const float4* __restrict__ other = pc4 + (size_t)b * N + mbase;
    const float qx = -2.f * p.x, qy = -2.f * p.y, qz = -2.f * p.z;
    float bda = FLTMAX, bdb = FLTMAX;
    #pragma unroll 2
    for (int j = 0; j < 256; j += 4) {
      float4 t0 = other[j], t1 = other[j + 1], t2 = other[j + 2], t3 = other[j + 3];
      float d0 = fmaf(qx, t0.x, fmaf(qy, t0.y, fmaf(qz, t0.z, t0.w)));
      float d1 = fmaf(qx, t1.x, fmaf(qy, t1.y, fmaf(qz, t1.z, t1.w)));
      float d2 = fmaf(qx, t2.x, fmaf(qy, t2.y, fmaf(qz, t2.z, t2.w)));
      float d3 = fmaf(qx, t3.x, fmaf(qy, t3.y, fmaf(qz, t3.z, t3.w)));
      bda = fminf(fminf(d0, d1), bda);   // -> v_min3
      bdb = fminf(fminf(d2, d3), bdb);
    }
    atomicMin(&best2[row], enc_f(fminf(bda, bdb) + p.w));
  }

  // Wait for THIS wave's atomics to reach the device coherence point.
  // (bare vmcnt wait — crucially NOT __threadfence(): no buffer_wbl2 L2 flush)
  __asm__ __volatile__("s_waitcnt vmcnt(0)" ::: "memory");
  if (tid == 0) tk = atomicAdd(&gcnt[(b << 4) + nc], 1u);
  __syncthreads();
  if (tk == MCHUNKS - 1) {       // last of the 16 mc-blocks: finalize (b,nc) rows
    unsigned long long k1 = __hip_atomic_load(&best1[row], __ATOMIC_RELAXED,
                                              __HIP_MEMORY_SCOPE_AGENT);
    unsigned k2 = __hip_atomic_load(&best2[row], __ATOMIC_RELAXED,
                                    __HIP_MEMORY_SCOPE_AGENT);
    float d1 = dec_f((unsigned)(k1 >> 32));
    int m = (int)(unsigned)(k1 & 0xFFFFFFFFull) & (N - 1);   // mask: OOB insurance
    float d2 = dec_f(k2);
    float4 a = pn4[row];
    float4 g = gn4[((size_t)b << 12) + m];
    float nl = 1.f - fabsf(a.x * g.x + a.y * g.y + a.z * g.z);
    float sd = block_sum_256(d1 + d2, s4);
    float sn = block_sum_256(nl, s4);
    if (tid == 0) {
      atomicAdd(&acc[0], sd);
      atomicAdd(&acc[1], sn);
      __asm__ __volatile__("s_waitcnt vmcnt(0)" ::: "memory");
      tk = atomicAdd(cnt, 1u);
    }
    __syncthreads();
    if (tk == NGROUP - 1) {      // last finalize group -> edge fold + out
      float e = (tid < SCAN_BLOCKS) ? edgep[tid] : 0.f;
      float te = block_sum_256(e, s4);
      if (tid == 0) {
        float chamf = atomicAdd(&acc[0], 0.f);
        float nsum  = atomicAdd(&acc[1], 0.f);
        float inv_bn = 1.f / (float)BN;
        out[0] = chamf * inv_bn + 0.1f * (nsum * inv_bn) + 0.5f * (te / (3.f * (float)BF));
      }
    }
  }
}

extern "C" void kernel_launch(void* const* d_in, const int* in_sizes, int n_in,
                              void* d_out, int out_size, void* d_ws, size_t ws_size,
                              hipStream_t stream) {
  const float* pv = (const float*)d_in[0];   // predicted_vertices [B,V,3]
  const int*   pf = (const int*)d_in[1];     // predicted_faces [F,3]
  // d_in[2]/d_in[3] (gt mesh) are unused by the reference.
  const float* rp = (const float*)d_in[4];   // rand_pred [B,N,3]
  const float* rg = (const float*)d_in[5];   // rand_gt   [B,N,3]
  float* out = (float*)d_out;

  unsigned long long* best1 = (unsigned long long*)d_ws;   // BN u64
  unsigned* best2 = (unsigned*)(best1 + BN);               // BN u32
  float4* pc4  = (float4*)(best2 + BN);                    // BN
  float4* pn4  = pc4 + BN;                                 // BN
  float4* gc4  = pn4 + BN;                                 // BN
  float4* gn4  = gc4 + BN;                                 // BN
  float4* nrm4 = gn4 + BN;                                 // BF
  float* cdf   = (float*)(nrm4 + BF);                      // BF
  float* csum  = cdf + BF;                                 // 216
  float* edgep = csum + SCAN_BLOCKS;                       // 216
  float* acc   = edgep + SCAN_BLOCKS;                      // 2
  unsigned* cnt  = (unsigned*)(acc + 2);                   // 1
  unsigned* gcnt = cnt + 1;                                // 128

  scan_faces_kernel<<<SCAN_BLOCKS, 256, 0, stream>>>(pv, pf, cdf, csum, nrm4, edgep,
                                                     best1, best2, acc, cnt, gcnt);
  sample_kernel<<<(2 * BN) / 256, 256, 0, stream>>>(pv, pf, cdf, csum, nrm4,
                                                    rp, rg, pc4, pn4, gc4, gn4);
  chamfer_kernel<<<2048, 256, 0, stream>>>(pc4, gc4, pn4, gn4, edgep,
                                           best1, best2, acc, cnt, gcnt, out);
}

// Round 9
// 123.850 us; speedup vs baseline: 2.1066x; 1.0268x over previous
//
#include <hip/hip_runtime.h>

#define EPSF 1e-12f
#define FLTMAX 3.402823466e+38f

constexpr int B = 8, V = 6890, F = 13776, N = 4096;
constexpr int BF = B * F;
constexpr int BN = B * N;
constexpr int CHUNK = 512;
constexpr int NCHUNK = (F + CHUNK - 1) / CHUNK;   // 27
constexpr int SCAN_BLOCKS = B * NCHUNK;           // 216

__device__ __forceinline__ float block_sum_256(float v, float* s4) {
  #pragma unroll
  for (int off = 32; off > 0; off >>= 1) v += __shfl_down(v, off, 64);
  __syncthreads();
  if ((threadIdx.x & 63) == 0) s4[threadIdx.x >> 6] = v;
  __syncthreads();
  return s4[0] + s4[1] + s4[2] + s4[3];
}

__device__ __forceinline__ float face_geom(const float* __restrict__ pv,
                                           const int* __restrict__ pf,
                                           int b, int f, float4* __restrict__ nrm4,
                                           float& es) {
  if (f >= F) return 0.f;
  int i0 = pf[f * 3 + 0], i1 = pf[f * 3 + 1], i2 = pf[f * 3 + 2];
  const float* vb = pv + (size_t)b * V * 3;
  float x0 = vb[i0 * 3 + 0], y0 = vb[i0 * 3 + 1], z0 = vb[i0 * 3 + 2];
  float x1 = vb[i1 * 3 + 0], y1 = vb[i1 * 3 + 1], z1 = vb[i1 * 3 + 2];
  float x2 = vb[i2 * 3 + 0], y2 = vb[i2 * 3 + 1], z2 = vb[i2 * 3 + 2];
  float ax = x1 - x0, ay = y1 - y0, az = z1 - z0;
  float bx = x2 - x0, by = y2 - y0, bz = z2 - z0;
  float cx = ay * bz - az * by;
  float cy = az * bx - ax * bz;
  float cz = ax * by - ay * bx;
  float cn = sqrtf(cx * cx + cy * cy + cz * cz);
  float inv = 1.f / (cn + EPSF);
  nrm4[(size_t)b * F + f] = make_float4(cx * inv, cy * inv, cz * inv, 0.f);
  float ex = x0 - x1, ey = y0 - y1, ez = z0 - z1;
  es += ex * ex + ey * ey + ez * ez;
  ex = x1 - x2; ey = y1 - y2; ez = z1 - z2;
  es += ex * ex + ey * ey + ez * ez;
  es += bx * bx + by * by + bz * bz;
  return 0.5f * cn;
}

// K1: face geometry + per-chunk scan + all init (best arrays, counters, acc).
__global__ __launch_bounds__(256) void scan_faces_kernel(
    const float* __restrict__ pv, const int* __restrict__ pf,
    float* __restrict__ cdf, float* __restrict__ csum, float4* __restrict__ nrm4,
    float* __restrict__ edgep,
    unsigned* __restrict__ best1, unsigned* __restrict__ best2,
    float* __restrict__ acc, unsigned* __restrict__ cnt) {
  __shared__ float wsum[4];
  __shared__ float s4[4];
  int b = blockIdx.x / NCHUNK, ck = blockIdx.x % NCHUNK;
  int lane = threadIdx.x & 63, wid = threadIdx.x >> 6;

  int gid = blockIdx.x * 256 + threadIdx.x;
  if (gid < BN) { best1[gid] = 0xFFFFFFFFu; best2[gid] = 0xFFFFFFFFu; }
  if (gid < 2) acc[gid] = 0.f;
  if (gid == 2) *cnt = 0u;

  int f0 = ck * CHUNK + 2 * threadIdx.x;
  float es = 0.f;
  float a0 = face_geom(pv, pf, b, f0, nrm4, es);
  float a1 = face_geom(pv, pf, b, f0 + 1, nrm4, es);
  float ts = a0 + a1;
  float x = ts;
  #pragma unroll
  for (int off = 1; off < 64; off <<= 1) {
    float y = __shfl_up(x, off, 64);
    if (lane >= off) x += y;
  }
  if (lane == 63) wsum[wid] = x;
  __syncthreads();
  float woff = 0.f;
  for (int w = 0; w < wid; ++w) woff += wsum[w];
  float excl = woff + x - ts;
  size_t g0 = (size_t)b * F + f0;
  if (f0 < F) cdf[g0] = excl + a0;
  if (f0 + 1 < F) cdf[g0 + 1] = excl + ts;
  if (threadIdx.x == 255) csum[blockIdx.x] = woff + x;   // raw chunk total

  float te = block_sum_256(es, s4);
  if (threadIdx.x == 0) edgep[blockIdx.x] = te;
}

// K2: sample 2*B*N points (on-the-fly chunk-total scan + in-chunk binary search).
__global__ __launch_bounds__(256) void sample_kernel(
    const float* __restrict__ pv, const int* __restrict__ pf,
    const float* __restrict__ cdf, const float* __restrict__ csum,
    const float4* __restrict__ nrm4,
    const float* __restrict__ rp, const float* __restrict__ rg,
    float4* __restrict__ pc4, float4* __restrict__ pn4,
    float4* __restrict__ gc4, float4* __restrict__ gn4) {
  int idx = blockIdx.x * 256 + threadIdx.x;
  if (idx >= 2 * BN) return;
  int set = (idx >= BN) ? 1 : 0;
  int i = idx - set * BN;
  int b = i / N;
  const float* r = (set ? rg : rp) + (size_t)i * 3;
  float u = r[0], r1 = r[1], r2 = r[2];

  const float* cs = csum + b * NCHUNK;
  float total = 0.f;
  #pragma unroll
  for (int k2 = 0; k2 < NCHUNK; ++k2) total += cs[k2];
  float target = u * (total + EPSF);

  int k = 0;
  float s = cs[0];
  while (s < target && k < NCHUNK - 1) { ++k; s += cs[k]; }
  float prefix = s - cs[k];
  float t2 = target - prefix;

  const float* c = cdf + (size_t)b * F + k * CHUNK;
  int base = k * CHUNK;
  int lo = 0, hi = CHUNK;
  while (lo < hi) {
    int mid = (lo + hi) >> 1;
    float v = (base + mid < F) ? c[mid] : FLTMAX;
    if (v < t2) lo = mid + 1; else hi = mid;
  }
  int f = base + lo;
  if (f > F - 1) f = F - 1;

  int i0 = pf[f * 3 + 0], i1 = pf[f * 3 + 1], i2 = pf[f * 3 + 2];
  const float* vb = pv + (size_t)b * V * 3;
  float su = sqrtf(r1);
  float w0 = 1.f - su, w1 = su * (1.f - r2), w2 = su * r2;
  float px = w0 * vb[i0 * 3 + 0] + w1 * vb[i1 * 3 + 0] + w2 * vb[i2 * 3 + 0];
  float py = w0 * vb[i0 * 3 + 1] + w1 * vb[i1 * 3 + 1] + w2 * vb[i2 * 3 + 1];
  float pz = w0 * vb[i0 * 3 + 2] + w1 * vb[i1 * 3 + 2] + w2 * vb[i2 * 3 + 2];
  float4* pts = (set ? gc4 : pc4);
  float4* pns = (set ? gn4 : pn4);
  pts[i] = make_float4(px, py, pz, px * px + py * py + pz * pz);
  pns[i] = nrm4[(size_t)b * F + f];
}

// K3: shared-d tiled chamfer. Each d[n,m] computed ONCE, feeds both row argmin
// (dist1, packed key = truncated-d | col-idx) and col min (dist2, raw bits).
// Block = 16x16 threads, 8x8 subtile each -> 128x128 tile. Grid 8192 = 8b x 32 x 32.
__global__ __launch_bounds__(256, 4) void chamfer_kernel(
    const float4* __restrict__ pc4, const float4* __restrict__ gc4,
    unsigned* __restrict__ best1, unsigned* __restrict__ best2) {
  const int tid = threadIdx.x;
  const int b = blockIdx.x >> 10;          // 1024 tiles/batch
  const int tn = (blockIdx.x >> 5) & 31;   // row tile (pc)
  const int tm = blockIdx.x & 31;          // col tile (gc)
  const int ty = tid >> 4, tx = tid & 15;
  const int r0 = tn * 128 + ty * 8;
  const int c0 = tm * 128 + tx * 8;
  const float4* __restrict__ prow = pc4 + (size_t)b * N + r0;
  const float4* __restrict__ gcol = gc4 + (size_t)b * N + c0;

  float qx[8], qy[8], qz[8], pp[8];
  float4 G[8];
  #pragma unroll
  for (int i = 0; i < 8; ++i) {
    float4 p = prow[i];
    qx[i] = -2.f * p.x; qy[i] = -2.f * p.y; qz[i] = -2.f * p.z; pp[i] = p.w;
  }
  #pragma unroll
  for (int j = 0; j < 8; ++j) G[j] = gcol[j];

  unsigned rkey[8], cbit[8];
  #pragma unroll
  for (int i = 0; i < 8; ++i) { rkey[i] = 0xFFFFFFFFu; cbit[i] = 0xFFFFFFFFu; }

  #pragma unroll
  for (int i = 0; i < 8; ++i) {
    #pragma unroll
    for (int j = 0; j < 8; ++j) {
      // d = |p|^2 + |g|^2 - 2 p.g  (>=0 up to fp noise; identical to reference form)
      float dp = fmaf(qx[i], G[j].x, fmaf(qy[i], G[j].y, fmaf(qz[i], G[j].z, G[j].w)));
      float d  = dp + pp[i];
      unsigned db = __float_as_uint(d);
      rkey[i] = min(rkey[i], (db & 0xFFFFF000u) | (unsigned)(c0 + j));  // v_and_or+v_min
      cbit[j] = min(cbit[j], db);                                       // raw-bit min
    }
  }

  __shared__ unsigned mrg[128][17];   // +1 pad
  // ---- row merge: 16 tx-threads per row ----
  #pragma unroll
  for (int i = 0; i < 8; ++i) mrg[ty * 8 + i][tx] = rkey[i];
  __syncthreads();
  if (tid < 128) {
    unsigned best = 0xFFFFFFFFu;
    #pragma unroll
    for (int k = 0; k < 16; ++k) best = min(best, mrg[tid][k]);
    atomicMin(&best1[(size_t)b * N + tn * 128 + tid], best);
  }
  __syncthreads();
  // ---- col merge: 16 ty-threads per col ----
  #pragma unroll
  for (int j = 0; j < 8; ++j) mrg[tx * 8 + j][ty] = cbit[j];
  __syncthreads();
  if (tid < 128) {
    unsigned best = 0xFFFFFFFFu;
    #pragma unroll
    for (int k = 0; k < 16; ++k) best = min(best, mrg[tid][k]);
    atomicMin(&best2[(size_t)b * N + tm * 128 + tid], best);
  }
}

// K4: finalize — row sums + normal loss; ticketed last block folds edge + writes out.
__global__ __launch_bounds__(256) void finalize_kernel(
    const unsigned* __restrict__ best1, const unsigned* __restrict__ best2,
    const float4* __restrict__ pn4, const float4* __restrict__ gn4,
    const float* __restrict__ edgep,
    float* __restrict__ acc, unsigned* __restrict__ cnt, float* __restrict__ out) {
  __shared__ float s4[4];
  __shared__ unsigned tk;
  int i = blockIdx.x * 256 + threadIdx.x;
  int b = i >> 12;
  unsigned k1 = best1[i];
  float d1 = __uint_as_float(k1 & 0xFFFFF000u);   // truncated min distance
  int m = (int)(k1 & 0xFFFu);                     // 12-bit col index (N=4096)
  float d2 = __uint_as_float(best2[i]);
  float4 a = pn4[i];
  float4 g = gn4[((size_t)b << 12) + m];
  float nl = 1.f - fabsf(a.x * g.x + a.y * g.y + a.z * g.z);
  float sd = block_sum_256(d1 + d2, s4);
  float sn = block_sum_256(nl, s4);
  if (threadIdx.x == 0) {
    atomicAdd(&acc[0], sd);
    atomicAdd(&acc[1], sn);
    __asm__ __volatile__("s_waitcnt vmcnt(0)" ::: "memory");
    tk = atomicAdd(cnt, 1u);
  }
  __syncthreads();
  if (tk == 127) {                     // last of 128 blocks
    float e = (threadIdx.x < SCAN_BLOCKS) ? edgep[threadIdx.x] : 0.f;
    float te = block_sum_256(e, s4);
    if (threadIdx.x == 0) {
      float chamf = atomicAdd(&acc[0], 0.f);
      float nsum  = atomicAdd(&acc[1], 0.f);
      float inv_bn = 1.f / (float)BN;
      out[0] = chamf * inv_bn + 0.1f * (nsum * inv_bn) + 0.5f * (te / (3.f * (float)BF));
    }
  }
}

extern "C" void kernel_launch(void* const* d_in, const int* in_sizes, int n_in,
                              void* d_out, int out_size, void* d_ws, size_t ws_size,
                              hipStream_t stream) {
  const float* pv = (const float*)d_in[0];   // predicted_vertices [B,V,3]
  const int*   pf = (const int*)d_in[1];     // predicted_faces [F,3]
  // d_in[2]/d_in[3] (gt mesh) are unused by the reference.
  const float* rp = (const float*)d_in[4];   // rand_pred [B,N,3]
  const float* rg = (const float*)d_in[5];   // rand_gt   [B,N,3]
  float* out = (float*)d_out;

  unsigned* best1 = (unsigned*)d_ws;                       // BN u32
  unsigned* best2 = best1 + BN;                            // BN u32
  float4* pc4  = (float4*)(best2 + BN);                    // BN
  float4* pn4  = pc4 + BN;                                 // BN
  float4* gc4  = pn4 + BN;                                 // BN
  float4* gn4  = gc4 + BN;                                 // BN
  float4* nrm4 = gn4 + BN;                                 // BF
  float* cdf   = (float*)(nrm4 + BF);                      // BF
  float* csum  = cdf + BF;                                 // 216
  float* edgep = csum + SCAN_BLOCKS;                       // 216
  float* acc   = edgep + SCAN_BLOCKS;                      // 2
  unsigned* cnt = (unsigned*)(acc + 2);                    // 1

  scan_faces_kernel<<<SCAN_BLOCKS, 256, 0, stream>>>(pv, pf, cdf, csum, nrm4, edgep,
                                                     best1, best2, acc, cnt);
  sample_kernel<<<(2 * BN) / 256, 256, 0, stream>>>(pv, pf, cdf, csum, nrm4,
                                                    rp, rg, pc4, pn4, gc4, gn4);
  chamfer_kernel<<<8 * 32 * 32, 256, 0, stream>>>(pc4, gc4, best1, best2);
  finalize_kernel<<<BN / 256, 256, 0, stream>>>(best1, best2, pn4, gn4, edgep,
                                                acc, cnt, out);
}